// Round 7
// baseline (744.812 us; speedup 1.0000x reference)
//
#include <hip/hip_runtime.h>

// Problem dims
constexpr int Bn = 64;     // batch
constexpr int Dn = 512;    // embed dim
constexpr int Mn = 1024;   // M
constexpr int Ln = 256;    // L
constexpr int Kn = 30;     // K heads
constexpr int KP = 32;     // K padded

typedef __attribute__((ext_vector_type(4))) float f32x4;

// ---------------------------------------------------------------------------
// thin GEMM v2: C[ks][b][mb*32+m][N] = A_mb[b][m,K] * B[b]
//   BT=false (NN): B[b][K,N], row stride Ndim.  BT=true (NT): B[b][N,K], row
//   stride Kdim. A row stride = Kdim; A staged as sum over aSlabs slabs.
// BM=32, BN=256, BK=32, 256 threads, acc 8x4/thread.
// grid (Ndim/256, mbCount*KS, Bn).
// ---------------------------------------------------------------------------
template <bool BT>
__global__ __launch_bounds__(256) void thin_gemm2(
    const float* __restrict__ A1, const float* __restrict__ A2,
    long sA1, long sA2, int M1, int M2,
    int aSlabs, long aSlabStride,
    const float* __restrict__ B, long sB,
    float* __restrict__ C, long sC, long slabC,
    int Ndim, int Kdim, int KS)
{
    constexpr int BM = 32, BN = 256, BK = 32;
    __shared__ float As[BK][BM + 4];
    __shared__ float Bs[BK][BN + 4];

    const int t  = threadIdx.x;
    const int nb = blockIdx.x;
    const int mb = blockIdx.y / KS, ks = blockIdx.y % KS;
    const int b  = blockIdx.z;
    const int n0 = nb * BN;
    const int kLen = Kdim / KS;
    const int k00  = ks * kLen;

    const float* Ab = (mb == 0) ? (A1 + (long)b * sA1) : (A2 + (long)b * sA2);
    const int Mreal = (mb == 0) ? M1 : M2;
    const float* Bb = B + (long)b * sB;

    const int tx = t & 63;          // n quad: cols tx*4..tx*4+3
    const int ty = t >> 6;          // m oct:  rows ty*8..ty*8+7

    float acc[8][4] = {};

    for (int k0 = k00; k0 < k00 + kLen; k0 += BK) {
        __syncthreads();
        // stage A (32x32), summing slabs
        {
            int kk = t & 31;
            #pragma unroll
            for (int i = 0; i < 4; i++) {
                int m = (t >> 5) + 8 * i;
                float v = 0.f;
                if (m < Mreal) {
                    long base = (long)m * Kdim + k0 + kk;
                    v = Ab[base];
                    for (int s = 1; s < aSlabs; s++)
                        v += Ab[(long)s * aSlabStride + base];
                }
                As[kk][m] = v;
            }
        }
        // stage B (32x256)
        if (BT) {
            int kk = t & 31;
            #pragma unroll
            for (int i = 0; i < 32; i++) {
                int n = (t >> 5) + 8 * i;
                Bs[kk][n] = Bb[(long)(n0 + n) * Kdim + k0 + kk];
            }
        } else {
            #pragma unroll
            for (int kk = 0; kk < BK; kk++)
                Bs[kk][t] = Bb[(long)(k0 + kk) * Ndim + n0 + t];
        }
        __syncthreads();
        #pragma unroll
        for (int kk = 0; kk < BK; kk++) {
            f32x4 alo = *(const f32x4*)&As[kk][ty * 8];
            f32x4 ahi = *(const f32x4*)&As[kk][ty * 8 + 4];
            f32x4 b4  = *(const f32x4*)&Bs[kk][tx * 4];
            #pragma unroll
            for (int j = 0; j < 4; j++) {
                acc[0][j] += alo.x * b4[j];
                acc[1][j] += alo.y * b4[j];
                acc[2][j] += alo.z * b4[j];
                acc[3][j] += alo.w * b4[j];
                acc[4][j] += ahi.x * b4[j];
                acc[5][j] += ahi.y * b4[j];
                acc[6][j] += ahi.z * b4[j];
                acc[7][j] += ahi.w * b4[j];
            }
        }
    }

    float* Cb = C + (long)ks * slabC + (long)b * sC;
    #pragma unroll
    for (int i = 0; i < 8; i++) {
        f32x4 v = {acc[i][0], acc[i][1], acc[i][2], acc[i][3]};
        *(f32x4*)&Cb[(long)(mb * BM + ty * 8 + i) * Ndim + n0 + tx * 4] = v;
    }
}

// ---------------------------------------------------------------------------
// fp32 tiled SGEMM with A-slab sum: C[M,N] = (Sum_s A_s)[M,K] * B[K,N]
// ---------------------------------------------------------------------------
__global__ __launch_bounds__(256) void sgemm2_kernel(
    const float* __restrict__ A, int aSlabs, long aSlabStride,
    const float* __restrict__ B,
    float* __restrict__ Cout, int Ndim, int Kdim)
{
    constexpr int BM = 64, BN = 64, BK = 16;
    __shared__ float As[BK][BM + 1];
    __shared__ float Bs[BK][BN + 1];

    const int tid = threadIdx.x;
    const int tx = tid & 15;
    const int ty = tid >> 4;
    const int row0 = blockIdx.y * BM + ty * 4;
    const int col0 = blockIdx.x * BN + tx * 4;

    float acc[4][4] = {};

    for (int k0 = 0; k0 < Kdim; k0 += BK) {
        #pragma unroll
        for (int i = 0; i < 4; i++) {
            int idx = tid + i * 256;
            int m  = idx >> 4;
            int kk = idx & 15;
            long base = (long)(blockIdx.y * BM + m) * Kdim + k0 + kk;
            float v = A[base];
            for (int s = 1; s < aSlabs; s++) v += A[(long)s * aSlabStride + base];
            As[kk][m] = v;
        }
        #pragma unroll
        for (int i = 0; i < 4; i++) {
            int idx = tid + i * 256;
            int kk = idx >> 6;
            int n  = idx & 63;
            Bs[kk][n] = B[(long)(k0 + kk) * Ndim + (blockIdx.x * BN + n)];
        }
        __syncthreads();
        #pragma unroll
        for (int kk = 0; kk < BK; kk++) {
            float a[4], bb[4];
            #pragma unroll
            for (int i = 0; i < 4; i++) a[i] = As[kk][ty * 4 + i];
            #pragma unroll
            for (int j = 0; j < 4; j++) bb[j] = Bs[kk][tx * 4 + j];
            #pragma unroll
            for (int i = 0; i < 4; i++)
                #pragma unroll
                for (int j = 0; j < 4; j++)
                    acc[i][j] += a[i] * bb[j];
        }
        __syncthreads();
    }

    #pragma unroll
    for (int i = 0; i < 4; i++)
        #pragma unroll
        for (int j = 0; j < 4; j++)
            Cout[(long)(row0 + i) * Ndim + col0 + j] = acc[i][j];
}

// ---------------------------------------------------------------------------
// fp32 transpose (W_b^T)
// ---------------------------------------------------------------------------
__global__ void transpose_f32_kernel(const float* __restrict__ X,
                                     float* __restrict__ Xt, int R, int C)
{
    __shared__ float tile[32][33];
    const int c0 = blockIdx.x * 32, r0 = blockIdx.y * 32;
    const int tx = threadIdx.x, ty = threadIdx.y;
    #pragma unroll
    for (int i = 0; i < 4; i++)
        tile[ty + 8 * i][tx] = X[(long)(r0 + ty + 8 * i) * C + c0 + tx];
    __syncthreads();
    #pragma unroll
    for (int i = 0; i < 4; i++)
        Xt[(long)(c0 + ty + 8 * i) * R + r0 + tx] = tile[tx][ty + 8 * i];
}

// ---------------------------------------------------------------------------
// sv + softmax fused: one block per b, 1024 threads.
// sv[m] = Sum_k whv[k] tanh(Sout[b][k][m] + Sout[b][32+k][m]); a_v = softmax(sv)
// ---------------------------------------------------------------------------
__global__ __launch_bounds__(1024) void sv_softmax_kernel(
    const float* __restrict__ Sout, const float* __restrict__ whv,
    float* __restrict__ a_v)
{
    const int b = blockIdx.x, t = threadIdx.x;
    __shared__ float wh[32];
    __shared__ float red[16];
    __shared__ float bc;
    if (t < 30) wh[t] = whv[t];
    __syncthreads();
    const float* Sb = Sout + (long)b * 64 * Mn;
    float s = 0.f;
    #pragma unroll
    for (int k = 0; k < Kn; k++)
        s += wh[k] * tanhf(Sb[(long)k * Mn + t] + Sb[(long)(32 + k) * Mn + t]);

    const int wid = t >> 6, lane = t & 63;
    float v = s;
    #pragma unroll
    for (int off = 32; off > 0; off >>= 1) v = fmaxf(v, __shfl_down(v, off, 64));
    if (lane == 0) red[wid] = v;
    __syncthreads();
    if (t == 0) {
        float mx = red[0];
        for (int i = 1; i < 16; i++) mx = fmaxf(mx, red[i]);
        bc = mx;
    }
    __syncthreads();
    const float e = expf(s - bc);
    v = e;
    #pragma unroll
    for (int off = 32; off > 0; off >>= 1) v += __shfl_down(v, off, 64);
    if (lane == 0) red[wid] = v;
    __syncthreads();
    if (t == 0) {
        float sm = 0.f;
        for (int i = 0; i < 16; i++) sm += red[i];
        bc = sm;
    }
    __syncthreads();
    a_v[(long)b * Mn + t] = e / bc;
}

// ---------------------------------------------------------------------------
// sq + softmax fused: one block per b, 256 threads. Sums 8 WqQ + 8 Tq slabs.
// ---------------------------------------------------------------------------
__global__ __launch_bounds__(256) void sq_softmax_kernel(
    const float* __restrict__ WqQp, const float* __restrict__ Tqp,
    const float* __restrict__ whq, float* __restrict__ a_q)
{
    const int b = blockIdx.x, t = threadIdx.x;
    __shared__ float wh[32];
    __shared__ float red[4];
    __shared__ float bc;
    if (t < 30) wh[t] = whq[t];
    __syncthreads();
    const long slab = (long)Bn * KP * Ln;
    const long base0 = (long)b * KP * Ln + t;
    float s = 0.f;
    #pragma unroll
    for (int k = 0; k < Kn; k++) {
        long base = base0 + (long)k * Ln;
        float w = 0.f, tq = 0.f;
        #pragma unroll
        for (int sl = 0; sl < 8; sl++) {
            w  += WqQp[(long)sl * slab + base];
            tq += Tqp [(long)sl * slab + base];
        }
        s += wh[k] * tanhf(w + tq);
    }
    const int wid = t >> 6, lane = t & 63;
    float v = s;
    #pragma unroll
    for (int off = 32; off > 0; off >>= 1) v = fmaxf(v, __shfl_down(v, off, 64));
    if (lane == 0) red[wid] = v;
    __syncthreads();
    if (t == 0) {
        float mx = red[0];
        for (int i = 1; i < 4; i++) mx = fmaxf(mx, red[i]);
        bc = mx;
    }
    __syncthreads();
    const float e = expf(s - bc);
    v = e;
    #pragma unroll
    for (int off = 32; off > 0; off >>= 1) v += __shfl_down(v, off, 64);
    if (lane == 0) red[wid] = v;
    __syncthreads();
    if (t == 0) {
        float sm = 0.f;
        for (int i = 0; i < 4; i++) sm += red[i];
        bc = sm;
    }
    __syncthreads();
    a_q[(long)b * Ln + t] = e / bc;
}

// ---------------------------------------------------------------------------
// v1[b,e] = Sum_m a_v[b,m] V[b,e,m]. Block 256 = 4 waves; wave w -> e.
// ---------------------------------------------------------------------------
__global__ __launch_bounds__(256) void poolv_kernel(
    const float* __restrict__ a_v, const float* __restrict__ V,
    float* __restrict__ v1)
{
    const int eb = blockIdx.x, b = blockIdx.y;
    const int t = threadIdx.x, w = t >> 6, lane = t & 63;
    const int e = eb * 4 + w;
    const float* vrow = V + ((long)b * Dn + e) * Mn;
    const float* av = a_v + (long)b * Mn;
    float acc = 0.f;
    #pragma unroll
    for (int i = 0; i < 4; i++) {
        f32x4 vv = *(const f32x4*)(vrow + 4 * lane + i * 256);
        f32x4 aa = *(const f32x4*)(av   + 4 * lane + i * 256);
        acc += vv.x * aa.x + vv.y * aa.y + vv.z * aa.z + vv.w * aa.w;
    }
    #pragma unroll
    for (int off = 32; off > 0; off >>= 1) acc += __shfl_down(acc, off, 64);
    if (lane == 0) v1[(long)b * Dn + e] = acc;
}

// ---------------------------------------------------------------------------
// poolq partials: pq[ls][b][e] = Sum_{l in chunk} a_q[b,l] Q[b,l,e]
// ---------------------------------------------------------------------------
__global__ __launch_bounds__(512) void poolq_kernel(
    const float* __restrict__ a_q, const float* __restrict__ Q,
    float* __restrict__ pq)
{
    const int ls = blockIdx.x, b = blockIdx.y, e = threadIdx.x;
    const float* aq = a_q + (long)b * Ln;
    float acc = 0.f;
    for (int l = ls * 64; l < ls * 64 + 64; l++)
        acc += aq[l] * Q[((long)b * Ln + l) * Dn + e];
    pq[((long)ls * Bn + b) * Dn + e] = acc;
}

// ---------------------------------------------------------------------------
// Broadcast outputs; q-part sums the 4 poolq partial slabs inline.
// ---------------------------------------------------------------------------
__global__ void bcast_kernel(const float* __restrict__ v1,
                             const float* __restrict__ pq,
                             float* __restrict__ out)
{
    const long nv4 = (long)Bn * Mn * Dn / 4;
    const long nq4 = (long)Bn * Ln * Dn / 4;
    long idx = (long)blockIdx.x * blockDim.x + threadIdx.x;
    float4* o4 = (float4*)out;
    if (idx < nv4) {
        long fidx = idx * 4;
        int e4 = (int)(fidx & (Dn - 1));
        long bm = fidx >> 9;
        int b = (int)(bm >> 10);
        o4[idx] = *(const float4*)(v1 + (long)b * Dn + e4);
    } else if (idx < nv4 + nq4) {
        long fidx = (idx - nv4) * 4;
        int e4 = (int)(fidx & (Dn - 1));
        long bl = fidx >> 9;
        int b = (int)(bl >> 8);
        f32x4 s = {0.f, 0.f, 0.f, 0.f};
        #pragma unroll
        for (int ls = 0; ls < 4; ls++) {
            f32x4 p = *(const f32x4*)(pq + ((long)ls * Bn + b) * Dn + e4);
            s.x += p.x; s.y += p.y; s.z += p.z; s.w += p.w;
        }
        float4 o = {s.x, s.y, s.z, s.w};
        o4[idx] = o;
    }
}

// ---------------------------------------------------------------------------

extern "C" void kernel_launch(void* const* d_in, const int* in_sizes, int n_in,
                              void* d_out, int out_size, void* d_ws, size_t ws_size,
                              hipStream_t stream)
{
    const float* V    = (const float*)d_in[0];  // [B, d, M]
    const float* Q    = (const float*)d_in[1];  // [B, L, d]
    const float* W_b  = (const float*)d_in[2];  // [d, d]
    const float* W_v  = (const float*)d_in[3];  // [K, d]
    const float* W_q  = (const float*)d_in[4];  // [K, d]
    const float* w_hv = (const float*)d_in[5];  // [K, 1]
    const float* w_hq = (const float*)d_in[6];  // [K, 1]
    float* out = (float*)d_out;

    // sizes (floats)
    const long szWqQ = (long)Bn * KP * Ln;   // 524288
    const long szU   = (long)Bn * KP * Dn;   // 1048576
    const long szSo  = (long)Bn * 64 * Mn;   // 4194304

    float* ws   = (float*)d_ws;
    float* WbT  = ws;                       // 262144
    float* WqQp = WbT  + 262144;            // 8 * szWqQ
    float* Up   = WqQp + 8 * szWqQ;         // 4 * szU
    float* P    = Up   + 4 * szU;           // szU
    float* Sout = P    + szU;               // szSo
    float* Rp   = Sout + szSo;              // 4 * szU
    float* G    = Rp   + 4 * szU;           // szU
    float* Tqp  = G    + szU;               // 8 * szWqQ
    float* a_v  = Tqp  + 8 * szWqQ;         // Bn*Mn
    float* a_q  = a_v  + (long)Bn * Mn;     // Bn*Ln
    float* v1   = a_q  + (long)Bn * Ln;     // Bn*Dn
    float* pq   = v1   + (long)Bn * Dn;     // 4*Bn*Dn

    // 0. WbT = W_b^T
    transpose_f32_kernel<<<dim3(Dn / 32, Dn / 32), dim3(32, 8), 0, stream>>>(
        W_b, WbT, Dn, Dn);

    // 1. WqQ[b,k,l] = Wq @ Q[b]^T : NT, N=256, K=512, KS=8 -> 8 slabs
    thin_gemm2<true><<<dim3(1, 8, Bn), 256, 0, stream>>>(
        W_q, W_q, 0, 0, Kn, Kn, 1, 0,
        Q, (long)Ln * Dn,
        WqQp, (long)KP * Ln, szWqQ, Ln, Dn, 8);

    // 2. U[b] = WqQ[b] @ Q[b] : NN, N=512, K=256, KS=4 (A = sum 8 WqQ slabs)
    thin_gemm2<false><<<dim3(2, 4, Bn), 256, 0, stream>>>(
        WqQp, WqQp, (long)KP * Ln, (long)KP * Ln, KP, KP, 8, szWqQ,
        Q, (long)Ln * Dn,
        Up, (long)KP * Dn, szU, Dn, Ln, 4);

    // 3. P = (sum 4 U slabs)[2048,512] @ W_b
    sgemm2_kernel<<<dim3(Dn / 64, Bn * KP / 64), 256, 0, stream>>>(
        Up, 4, szU, W_b, P, Dn, Dn);

    // 4. Sout[b] = [W_v | P[b]] @ V[b] : NN, N=1024, K=512, mb 2, KS=1
    thin_gemm2<false><<<dim3(4, 2, Bn), 256, 0, stream>>>(
        W_v, P, 0, (long)KP * Dn, Kn, KP, 1, 0,
        V, (long)Dn * Mn,
        Sout, (long)64 * Mn, 0, Mn, Dn, 1);

    // 5. a_v = softmax_m( Sum_k whv tanh(WvV + Tv) )
    sv_softmax_kernel<<<Bn, 1024, 0, stream>>>(Sout, w_hv, a_v);

    // 6. R[b] = WvV[b] @ V[b]^T : NT, N=512, K=1024, KS=4 -> 4 slabs
    thin_gemm2<true><<<dim3(2, 4, Bn), 256, 0, stream>>>(
        Sout, Sout, (long)64 * Mn, (long)64 * Mn, KP, KP, 1, 0,
        V, (long)Dn * Mn,
        Rp, (long)KP * Dn, szU, Dn, Mn, 4);

    // 7. G = (sum 4 R slabs)[2048,512] @ WbT
    sgemm2_kernel<<<dim3(Dn / 64, Bn * KP / 64), 256, 0, stream>>>(
        Rp, 4, szU, WbT, G, Dn, Dn);

    // 8. Tq[b,k,l] = G[b] @ Q[b]^T : NT, N=256, K=512, KS=8 -> 8 slabs
    thin_gemm2<true><<<dim3(1, 8, Bn), 256, 0, stream>>>(
        G, G, (long)KP * Dn, (long)KP * Dn, KP, KP, 1, 0,
        Q, (long)Ln * Dn,
        Tqp, (long)KP * Ln, szWqQ, Ln, Dn, 8);

    // 9. a_q = softmax_l( Sum_k whq tanh(WqQ + Tq) ), slab sums inline
    sq_softmax_kernel<<<Bn, Ln, 0, stream>>>(WqQp, Tqp, w_hq, a_q);

    // 10. pooling
    poolv_kernel<<<dim3(Dn / 4, Bn), 256, 0, stream>>>(a_v, V, v1);
    poolq_kernel<<<dim3(4, Bn), Dn, 0, stream>>>(a_q, Q, pq);

    // 11. broadcast outputs (q1 slab-sum inline)
    {
        long n4 = (long)Bn * Mn * Dn / 4 + (long)Bn * Ln * Dn / 4;
        bcast_kernel<<<(int)((n4 + 255) / 256), 256, 0, stream>>>(v1, pq, out);
    }
}